// Round 4
// baseline (187.647 us; speedup 1.0000x reference)
//
#include <hip/hip_runtime.h>

// Problem constants: B=1024, D=64, M=3, C=16384
#define B_  1024
#define D_  64
#define M_  3
#define C_  16384
#define CS  512            // c-rows per grid.y chunk  -> grid.y = 32
#define NT  (CS / 16)      // c-tiles per wave = 32

typedef __attribute__((ext_vector_type(8))) short bf16x8;   // MFMA A/B frag
typedef __attribute__((ext_vector_type(4))) float f32x4;    // MFMA acc

// truncating fp32 -> bf16 pack: 1 v_perm_b32 per 2 floats
__device__ __forceinline__ bf16x8 pack8(float4 x, float4 y) {
    union { unsigned u[4]; bf16x8 v; } r;
    r.u[0] = __builtin_amdgcn_perm(__float_as_uint(x.y), __float_as_uint(x.x), 0x07060302u);
    r.u[1] = __builtin_amdgcn_perm(__float_as_uint(x.w), __float_as_uint(x.z), 0x07060302u);
    r.u[2] = __builtin_amdgcn_perm(__float_as_uint(y.y), __float_as_uint(y.x), 0x07060302u);
    r.u[3] = __builtin_amdgcn_perm(__float_as_uint(y.w), __float_as_uint(y.z), 0x07060302u);
    return r.v;
}

__device__ __forceinline__ float fexp2(float x) {   // 2^x, single VALU op
    float r; asm("v_exp_f32 %0, %1" : "=v"(r) : "v"(x)); return r;
}

// ---------------------------------------------------------------------------
// Workspace (floats): ws[0]=accum, ws[16 .. 16+2*M*B)=wsum[2][M][B]  (~25 KB)
// ---------------------------------------------------------------------------

__global__ __launch_bounds__(256) void zero_ws(float* __restrict__ ws) {
    int i = blockIdx.x * 256 + threadIdx.x;   // grid 25 -> 6400 >= 6160
    if (i < 16 + 2 * M_ * B_) ws[i] = 0.0f;
}

// grid (B/128, C/CS, M*2). Wave owns 32 b-cols (B-frags in regs), loops a
// 512-row c-chunk with double-buffered A/conc prefetch; exp-sums accumulate
// in registers; 2 atomics per wave at the end.
__global__ __launch_bounds__(256) void lse_mfma(
    const float* __restrict__ cen0, const float* __restrict__ cen1,
    const float* __restrict__ f0,   const float* __restrict__ f1,
    const float* __restrict__ conc0,const float* __restrict__ conc1,
    float* __restrict__ wsum)       // [2][M][B]
{
    const int z  = blockIdx.z;
    const int br = z & 1, m = z >> 1;
    const float* __restrict__ cen  = br ? cen1  : cen0;
    const float* __restrict__ ft   = br ? f1    : f0;
    const float* __restrict__ conc = br ? conc1 : conc0;
    float* __restrict__ wsm = wsum + (br * M_ + m) * B_;

    const int wave = threadIdx.x >> 6;
    const int lane = threadIdx.x & 63;
    const int lrow = lane & 15;
    const int lk   = lane >> 4;                 // k-group 0..3
    const int wb   = blockIdx.x * 128 + wave * 32;   // first b-col of wave

    // --- B fragments (features, fp32 -> bf16 truncate), resident ----------
    bf16x8 bfr[2][2];
#pragma unroll
    for (int t = 0; t < 2; ++t) {
        const float* fp = ft + (size_t)(wb + t * 16 + lrow) * D_ + lk * 8;
#pragma unroll
        for (int kk = 0; kk < 2; ++kk) {
            float4 x = *reinterpret_cast<const float4*>(fp + kk * 32);
            float4 y = *reinterpret_cast<const float4*>(fp + kk * 32 + 4);
            bfr[t][kk] = pack8(x, y);
        }
    }

    const int c0 = blockIdx.y * CS;
    const float* ap = cen + (size_t)(m * C_ + c0 + lrow) * D_ + lk * 8;
    const float* ip = conc + m * C_ + c0 + lk * 4;

    // --- prefetch tile 0 ---------------------------------------------------
    float4 a0n = *reinterpret_cast<const float4*>(ap);
    float4 a1n = *reinterpret_cast<const float4*>(ap + 4);
    float4 a2n = *reinterpret_cast<const float4*>(ap + 32);
    float4 a3n = *reinterpret_cast<const float4*>(ap + 36);
    float4 icn = *reinterpret_cast<const float4*>(ip);

    const float LOG2E = 1.44269504088896340736f;
    float s0 = 0.0f, s1 = 0.0f;

    for (int ct = 0; ct < NT; ++ct) {
        float4 a0 = a0n, a1 = a1n, a2 = a2n, a3 = a3n, cc = icn;
        if (ct + 1 < NT) {                       // prefetch next tile
            ap += 16 * D_; ip += 16;
            a0n = *reinterpret_cast<const float4*>(ap);
            a1n = *reinterpret_cast<const float4*>(ap + 4);
            a2n = *reinterpret_cast<const float4*>(ap + 32);
            a3n = *reinterpret_cast<const float4*>(ap + 36);
            icn = *reinterpret_cast<const float4*>(ip);
        }
        const bf16x8 af0 = pack8(a0, a1);        // d 0..31
        const bf16x8 af1 = pack8(a2, a3);        // d 32..63

        f32x4 acc0 = {0.f, 0.f, 0.f, 0.f};
        f32x4 acc1 = {0.f, 0.f, 0.f, 0.f};
        acc0 = __builtin_amdgcn_mfma_f32_16x16x32_bf16(af0, bfr[0][0], acc0, 0, 0, 0);
        acc0 = __builtin_amdgcn_mfma_f32_16x16x32_bf16(af1, bfr[0][1], acc0, 0, 0, 0);
        acc1 = __builtin_amdgcn_mfma_f32_16x16x32_bf16(af0, bfr[1][0], acc1, 0, 0, 0);
        acc1 = __builtin_amdgcn_mfma_f32_16x16x32_bf16(af1, bfr[1][1], acc1, 0, 0, 0);

        // epilogue: s += 2^( acc * log2e/conc )  (rows = lk*4+j)
        float ic[4];
#pragma unroll
        for (int j = 0; j < 4; ++j)
            ic[j] = __builtin_amdgcn_rcpf(cc[j]) * LOG2E;
#pragma unroll
        for (int j = 0; j < 4; ++j) {
            s0 += fexp2(acc0[j] * ic[j]);
            s1 += fexp2(acc1[j] * ic[j]);
        }
    }

    // reduce over the 4 k-groups (rows) -> per-col totals in lanes 0..15
    s0 += __shfl_xor(s0, 16); s0 += __shfl_xor(s0, 32);
    s1 += __shfl_xor(s1, 16); s1 += __shfl_xor(s1, 32);
    if (lane < 16) {
        atomicAdd(&wsm[wb + lane], s0);
        atomicAdd(&wsm[wb + 16 + lane], s1);
    }
}

// Both branches in one launch: term = pos_logit - log(wsum); wave-reduce,
// one atomic per wave.
__global__ __launch_bounds__(256) void finish_all(
    const float* __restrict__ f,    const float* __restrict__ f_I,
    const float* __restrict__ cen0, const float* __restrict__ cen1,
    const float* __restrict__ conc0,const float* __restrict__ conc1,
    const int*   __restrict__ lab0, const int*   __restrict__ lab1,
    const float* __restrict__ wsum, float* __restrict__ accum)
{
    const int idx = blockIdx.x * 256 + threadIdx.x;   // 0 .. 2*M*B-1
    const int br  = idx / (M_ * B_);
    const int r   = idx - br * (M_ * B_);
    const int m   = r / B_;
    const int b   = r - m * B_;

    const float* cen  = br ? cen1  : cen0;
    const float* conc = br ? conc1 : conc0;
    const int*   lab  = br ? lab1  : lab0;
    const float* ft   = br ? f     : f_I;

    const int c = lab[r];
    const float* cr   = cen + (size_t)(m * C_ + c) * D_;
    const float* frow = ft + (size_t)b * D_;
    float a0 = 0.f, a1 = 0.f, a2 = 0.f, a3 = 0.f;
#pragma unroll
    for (int d = 0; d < D_; d += 4) {
        a0 = fmaf(cr[d + 0], frow[d + 0], a0);
        a1 = fmaf(cr[d + 1], frow[d + 1], a1);
        a2 = fmaf(cr[d + 2], frow[d + 2], a2);
        a3 = fmaf(cr[d + 3], frow[d + 3], a3);
    }
    const float logit = ((a0 + a1) + (a2 + a3)) / conc[(size_t)m * C_ + c];
    float term = logit - __logf(wsum[idx]);

#pragma unroll
    for (int off = 32; off > 0; off >>= 1)
        term += __shfl_down(term, off);
    if ((threadIdx.x & 63) == 0)
        atomicAdd(accum, term);
}

__global__ void finalize(const float* __restrict__ accum,
                         const int*   __restrict__ lb,
                         float* __restrict__ out)
{
    out[0] = (1.0f / (float)B_) * (float)lb[0] * (-1.0f / (float)M_) * 0.5f
             * accum[0];
}

extern "C" void kernel_launch(void* const* d_in, const int* in_sizes, int n_in,
                              void* d_out, int out_size, void* d_ws, size_t ws_size,
                              hipStream_t stream) {
    const float* f      = (const float*)d_in[0];
    const float* f_I    = (const float*)d_in[1];
    const float* cen    = (const float*)d_in[2];
    const float* cen_I  = (const float*)d_in[3];
    const float* conc   = (const float*)d_in[4];
    const float* conc_I = (const float*)d_in[5];
    const int*   lab    = (const int*)d_in[6];
    const int*   lab_I  = (const int*)d_in[7];
    const int*   lb     = (const int*)d_in[8];

    float* ws    = (float*)d_ws;
    float* accum = ws;
    float* wsum  = ws + 16;            // [2][M][B]
    float* out   = (float*)d_out;

    zero_ws<<<25, 256, 0, stream>>>(ws);

    dim3 g(B_ / 128, C_ / CS, M_ * 2);
    // branch 0: cen x features_I ; branch 1: cen_I x features
    lse_mfma<<<g, 256, 0, stream>>>(cen, cen_I, f_I, f, conc, conc_I, wsum);

    finish_all<<<(2 * M_ * B_) / 256, 256, 0, stream>>>(
        f, f_I, cen, cen_I, conc, conc_I, lab, lab_I, wsum, accum);

    finalize<<<1, 1, 0, stream>>>(accum, lb, out);
}

// Round 5
// 143.760 us; speedup vs baseline: 1.3053x; 1.3053x over previous
//
#include <hip/hip_runtime.h>

// Problem constants: B=1024, D=64, M=3, C=16384
#define B_  1024
#define D_  64
#define M_  3
#define C_  16384

typedef __attribute__((ext_vector_type(8))) short bf16x8;   // MFMA A/B frag
typedef __attribute__((ext_vector_type(4))) float f32x4;    // MFMA acc

// truncating fp32 -> bf16 pack (validated R2/R4): low short = first arg
__device__ __forceinline__ unsigned bfpack2(float lo, float hi) {
    return __builtin_amdgcn_perm(__float_as_uint(hi), __float_as_uint(lo),
                                 0x07060302u);
}
__device__ __forceinline__ bf16x8 pack8(float4 x, float4 y) {
    union { unsigned u[4]; bf16x8 v; } r;
    r.u[0] = bfpack2(x.x, x.y);
    r.u[1] = bfpack2(x.z, x.w);
    r.u[2] = bfpack2(y.x, y.y);
    r.u[3] = bfpack2(y.z, y.w);
    return r.v;
}
__device__ __forceinline__ float fexp2(float x) {   // 2^x, one v_exp_f32
    float r; asm("v_exp_f32 %0, %1" : "=v"(r) : "v"(x)); return r;
}

// ---------------------------------------------------------------------------
// Workspace layout (floats):
//   ws[0 .. 6144)     wsum [2][M][B]          (zeroed by prep)
//   ws[6144 .. 6272)  wsred[96] finish-wave partials (zeroed by prep)
//   ws[6400 .. )      fb0 [B*D] ushort, fb1 [B*D] ushort  (bf16 features)
// total ~282 KB (same ballpark as the R2 kernel that passed).
// ---------------------------------------------------------------------------

// Convert both feature matrices fp32 -> bf16 (trunc) and zero wsum/wsred.
__global__ __launch_bounds__(256) void prep(
    const float* __restrict__ f, const float* __restrict__ f_I,
    unsigned short* __restrict__ fb0, unsigned short* __restrict__ fb1,
    float* __restrict__ wz)
{
    const int t = blockIdx.x * 256 + threadIdx.x;   // grid 64 -> 16384
    const float4 a = reinterpret_cast<const float4*>(f_I)[t];  // branch 0
    const float4 b = reinterpret_cast<const float4*>(f)[t];    // branch 1
    uint2 pa, pb;
    pa.x = bfpack2(a.x, a.y); pa.y = bfpack2(a.z, a.w);
    pb.x = bfpack2(b.x, b.y); pb.y = bfpack2(b.z, b.w);
    reinterpret_cast<uint2*>(fb0)[t] = pa;
    reinterpret_cast<uint2*>(fb1)[t] = pb;
    if (t < 6272) wz[t] = 0.0f;
}

// grid (C/128, M, 2), block 256 (4 waves x 32 c-rows = 128 rows/block).
// Each c-row is read from HBM exactly once (A-frags register-resident,
// pre-scaled by LOG2E/conc so the epilogue is just exp2+add). Waves loop
// all 64 b-tiles; per tile a fire-and-forget LDS atomic accumulates the
// 16 column partials; block-end does 1024 global atomics into wsum.
__global__ __launch_bounds__(256) void lse_mfma(
    const float* __restrict__ cen0, const float* __restrict__ cen1,
    const unsigned short* __restrict__ fb0, const unsigned short* __restrict__ fb1,
    const float* __restrict__ conc0, const float* __restrict__ conc1,
    float* __restrict__ wsum)       // [2][M][B]
{
    const int br = blockIdx.z;
    const int m  = blockIdx.y;
    const float* __restrict__ cen  = br ? cen1  : cen0;
    const float* __restrict__ conc = br ? conc1 : conc0;
    const unsigned short* __restrict__ fb = br ? fb1 : fb0;

    __shared__ float lsum[B_];
    for (int i = threadIdx.x; i < B_; i += 256) lsum[i] = 0.0f;
    __syncthreads();

    const int wave = threadIdx.x >> 6;
    const int lane = threadIdx.x & 63;
    const int lrow = lane & 15;
    const int lk   = lane >> 4;                 // k-group 0..3
    const float LOG2E = 1.44269504088896340736f;

    // --- A fragments: 2 c-tiles, pre-scaled by LOG2E/conc[row], bf16 ------
    bf16x8 af[2][2];
#pragma unroll
    for (int t = 0; t < 2; ++t) {
        const int row = blockIdx.x * 128 + wave * 32 + t * 16 + lrow;
        const float sc = LOG2E * __builtin_amdgcn_rcpf(conc[m * C_ + row]);
        const float* cp = cen + (size_t)(m * C_ + row) * D_ + lk * 8;
        float4 x0 = *reinterpret_cast<const float4*>(cp);
        float4 x1 = *reinterpret_cast<const float4*>(cp + 4);
        float4 y0 = *reinterpret_cast<const float4*>(cp + 32);
        float4 y1 = *reinterpret_cast<const float4*>(cp + 36);
        x0.x *= sc; x0.y *= sc; x0.z *= sc; x0.w *= sc;
        x1.x *= sc; x1.y *= sc; x1.z *= sc; x1.w *= sc;
        y0.x *= sc; y0.y *= sc; y0.z *= sc; y0.w *= sc;
        y1.x *= sc; y1.y *= sc; y1.z *= sc; y1.w *= sc;
        af[t][0] = pack8(x0, x1);   // k = 0..31 slot
        af[t][1] = pack8(y0, y1);   // k = 32..63 slot
    }

    // --- b-tile loop with 1-deep B-frag prefetch ---------------------------
    const unsigned short* fp = fb + lrow * D_ + lk * 8;
    bf16x8 nb0 = *reinterpret_cast<const bf16x8*>(fp);
    bf16x8 nb1 = *reinterpret_cast<const bf16x8*>(fp + 32);

    for (int bt = 0; bt < B_ / 16; ++bt) {
        const bf16x8 b0 = nb0, b1 = nb1;
        if (bt + 1 < B_ / 16) {
            const unsigned short* np = fp + (size_t)(bt + 1) * 16 * D_;
            nb0 = *reinterpret_cast<const bf16x8*>(np);
            nb1 = *reinterpret_cast<const bf16x8*>(np + 32);
        }
        f32x4 acc0 = {0.f, 0.f, 0.f, 0.f};
        f32x4 acc1 = {0.f, 0.f, 0.f, 0.f};
        acc0 = __builtin_amdgcn_mfma_f32_16x16x32_bf16(af[0][0], b0, acc0, 0, 0, 0);
        acc0 = __builtin_amdgcn_mfma_f32_16x16x32_bf16(af[0][1], b1, acc0, 0, 0, 0);
        acc1 = __builtin_amdgcn_mfma_f32_16x16x32_bf16(af[1][0], b0, acc1, 0, 0, 0);
        acc1 = __builtin_amdgcn_mfma_f32_16x16x32_bf16(af[1][1], b1, acc1, 0, 0, 0);

        // epilogue: acc already includes log2e/conc -> pure exp2 + tree add
        const float e0 = fexp2(acc0[0]), e1 = fexp2(acc0[1]);
        const float e2 = fexp2(acc0[2]), e3 = fexp2(acc0[3]);
        const float e4 = fexp2(acc1[0]), e5 = fexp2(acc1[1]);
        const float e6 = fexp2(acc1[2]), e7 = fexp2(acc1[3]);
        float s = ((e0 + e1) + (e2 + e3)) + ((e4 + e5) + (e6 + e7));

        // reduce over the 4 k-groups (c-rows) -> col totals in lanes 0..15
        s += __shfl_xor(s, 16);
        s += __shfl_xor(s, 32);
        if (lane < 16) atomicAdd(&lsum[bt * 16 + lane], s);   // ds_add_f32
    }

    __syncthreads();
    float* __restrict__ wdst = wsum + (br * M_ + m) * B_;
    for (int i = threadIdx.x; i < B_; i += 256)
        atomicAdd(&wdst[i], lsum[i]);
}

// Per (m,b): term = pos_logit - ln(wsum). Wave-reduce, plain store per wave.
__global__ __launch_bounds__(256) void finish(
    const float* __restrict__ f,    const float* __restrict__ f_I,
    const float* __restrict__ cen0, const float* __restrict__ cen1,
    const float* __restrict__ conc0,const float* __restrict__ conc1,
    const int*   __restrict__ lab0, const int*   __restrict__ lab1,
    const float* __restrict__ wsum, float* __restrict__ wsred)
{
    const int idx = blockIdx.x * 256 + threadIdx.x;   // 0 .. 2*M*B-1
    const int br  = idx / (M_ * B_);
    const int r   = idx - br * (M_ * B_);
    const int m   = r / B_;
    const int b   = r - m * B_;

    const float* cen  = br ? cen1  : cen0;
    const float* conc = br ? conc1 : conc0;
    const int*   lab  = br ? lab1  : lab0;
    const float* ft   = br ? f     : f_I;

    const int c = lab[r];
    const float* cr   = cen + (size_t)(m * C_ + c) * D_;
    const float* frow = ft + (size_t)b * D_;
    float a0 = 0.f, a1 = 0.f, a2 = 0.f, a3 = 0.f;
#pragma unroll
    for (int d = 0; d < D_; d += 4) {
        a0 = fmaf(cr[d + 0], frow[d + 0], a0);
        a1 = fmaf(cr[d + 1], frow[d + 1], a1);
        a2 = fmaf(cr[d + 2], frow[d + 2], a2);
        a3 = fmaf(cr[d + 3], frow[d + 3], a3);
    }
    const float logit = ((a0 + a1) + (a2 + a3)) / conc[(size_t)m * C_ + c];
    float term = logit - __logf(wsum[idx]);

#pragma unroll
    for (int off = 32; off > 0; off >>= 1)
        term += __shfl_down(term, off);
    if ((threadIdx.x & 63) == 0)
        wsred[idx >> 6] = term;            // 96 slots, plain store
}

// Single wave: sum the 96 finish-wave partials, scale, write the output.
__global__ void finalize(const float* __restrict__ wsred,
                         const int*   __restrict__ lb,
                         float* __restrict__ out)
{
    const int t = threadIdx.x;             // 64 threads
    float v = wsred[t];
    if (t < 32) v += wsred[64 + t];
#pragma unroll
    for (int off = 32; off > 0; off >>= 1)
        v += __shfl_down(v, off);
    if (t == 0)
        out[0] = (1.0f / (float)B_) * (float)lb[0] * (-1.0f / (float)M_)
                 * 0.5f * v;
}

extern "C" void kernel_launch(void* const* d_in, const int* in_sizes, int n_in,
                              void* d_out, int out_size, void* d_ws, size_t ws_size,
                              hipStream_t stream) {
    const float* f      = (const float*)d_in[0];
    const float* f_I    = (const float*)d_in[1];
    const float* cen    = (const float*)d_in[2];
    const float* cen_I  = (const float*)d_in[3];
    const float* conc   = (const float*)d_in[4];
    const float* conc_I = (const float*)d_in[5];
    const int*   lab    = (const int*)d_in[6];
    const int*   lab_I  = (const int*)d_in[7];
    const int*   lb     = (const int*)d_in[8];

    float* ws    = (float*)d_ws;
    float* wsum  = ws;                     // [2][M][B] = 6144
    float* wsred = ws + 6144;              // 96 (+pad)
    unsigned short* fb0 = (unsigned short*)(ws + 6400);
    unsigned short* fb1 = fb0 + B_ * D_;
    float* out = (float*)d_out;

    prep<<<64, 256, 0, stream>>>(f, f_I, fb0, fb1, wsum);

    dim3 g(C_ / 128, M_, 2);
    // branch 0: cen x features_I ; branch 1: cen_I x features
    lse_mfma<<<g, 256, 0, stream>>>(cen, cen_I, fb0, fb1, conc, conc_I, wsum);

    finish<<<(2 * M_ * B_) / 256, 256, 0, stream>>>(
        f, f_I, cen, cen_I, conc, conc_I, lab, lab_I, wsum, wsred);

    finalize<<<1, 64, 0, stream>>>(wsred, lb, out);
}